// Round 1
// baseline (576.578 us; speedup 1.0000x reference)
//
#include <hip/hip_runtime.h>
#include <stdint.h>

#define M_DIM 8192
#define N_DIM 4096
#define K_DIM 4096

typedef float f32x4 __attribute__((ext_vector_type(4)));

// ---------------- init: zero the two amax slots ----------------
__global__ void init_ws_kernel(unsigned int* ws_u) {
    ws_u[0] = 0u;
    ws_u[1] = 0u;
}

// ---------------- amax reduction (abs-max via uint-bits atomicMax) -------
__global__ __launch_bounds__(256) void amax_kernel(const float* __restrict__ in,
                                                   int n4,
                                                   unsigned int* __restrict__ target) {
    int tid = blockIdx.x * blockDim.x + threadIdx.x;
    int stride = gridDim.x * blockDim.x;
    const float4* p = (const float4*)in;
    float m = 0.0f;
    for (int i = tid; i < n4; i += stride) {
        float4 v = p[i];
        m = fmaxf(m, fmaxf(fmaxf(fabsf(v.x), fabsf(v.y)),
                           fmaxf(fabsf(v.z), fabsf(v.w))));
    }
#pragma unroll
    for (int off = 32; off > 0; off >>= 1)
        m = fmaxf(m, __shfl_down(m, off, 64));
    __shared__ float sm[4];
    if ((threadIdx.x & 63) == 0) sm[threadIdx.x >> 6] = m;
    __syncthreads();
    if (threadIdx.x == 0) {
        m = fmaxf(fmaxf(sm[0], sm[1]), fmaxf(sm[2], sm[3]));
        atomicMax(target, __float_as_uint(m));  // all values >= 0: bit order == float order
    }
}

// ---------------- quantize f32 -> fp8 e4m3fn (packed 4/uint) ----------------
__global__ __launch_bounds__(256) void quant_kernel(const float* __restrict__ in,
                                                    unsigned int* __restrict__ outp,
                                                    int n4,
                                                    const unsigned int* __restrict__ ws_u,
                                                    int slot) {
    float amax = fmaxf(__uint_as_float(ws_u[slot]), 1e-12f);
    float scale = 448.0f / amax;
    int tid = blockIdx.x * blockDim.x + threadIdx.x;
    int stride = gridDim.x * blockDim.x;
    const float4* p = (const float4*)in;
    for (int i = tid; i < n4; i += stride) {
        float4 v = p[i];
        float a = fminf(fmaxf(v.x * scale, -448.0f), 448.0f);
        float b = fminf(fmaxf(v.y * scale, -448.0f), 448.0f);
        float c = fminf(fmaxf(v.z * scale, -448.0f), 448.0f);
        float d = fminf(fmaxf(v.w * scale, -448.0f), 448.0f);
        int w = __builtin_amdgcn_cvt_pk_fp8_f32(a, b, 0, false);   // bytes 0,1
        w = __builtin_amdgcn_cvt_pk_fp8_f32(c, d, w, true);        // bytes 2,3
        outp[i] = (unsigned int)w;
    }
}

// ---------------- fp8 GEMM: out[t][o] = inv * sum_k Xq[t][k]*Wq[o][k] + bias[o] ----
__device__ __forceinline__ void gld16(const void* g, void* l) {
    __builtin_amdgcn_global_load_lds(
        (const __attribute__((address_space(1))) void*)g,
        (__attribute__((address_space(3))) void*)l, 16, 0, 0);
}

__global__ __launch_bounds__(256, 2) void gemm_fp8_kernel(
    const uint8_t* __restrict__ Aq,   // [M][K] fp8
    const uint8_t* __restrict__ Bq,   // [N][K] fp8 (weight, K-major)
    const float* __restrict__ bias,   // [N]
    const unsigned int* __restrict__ ws_u,
    float* __restrict__ out)          // [M][N] f32
{
    __shared__ uint8_t lA[128 * 64];
    __shared__ uint8_t lB[128 * 64];

    const int tid = threadIdx.x;
    const int w = tid >> 6, l = tid & 63;

    // XCD-aware swizzle (gridDim.x == 2048, divisible by 8)
    const int nwg = gridDim.x;
    const int cpx = nwg >> 3;
    const int bid = blockIdx.x;
    const int swz = (bid & 7) * cpx + (bid >> 3);
    const int NT = N_DIM / 128;          // 32 col-tiles
    const int bm = swz / NT, bn = swz % NT;

    const uint8_t* gA = Aq + (size_t)bm * 128 * K_DIM;
    const uint8_t* gB = Bq + (size_t)bn * 128 * K_DIM;

    // staging map: thread t loads 16B; lds byte off = t*16 (+4096 for 2nd half)
    // row = off/64, col = off%64  ->  global row = i*64 + t/4, col = (t&3)*16
    const int tRow = tid >> 2;
    const int tCol = (tid & 3) << 4;

    f32x4 acc[4][4] = {};
    const int wr = w >> 1, wc = w & 1;   // 2x2 wave grid, 64x64 per wave
    const int lr = l & 15;
    const int lk = (l >> 4) << 3;        // k-byte offset within 32-wide k group

    for (int k0 = 0; k0 < K_DIM; k0 += 64) {
        gld16(gA + (size_t)tRow * K_DIM + k0 + tCol,        &lA[tid * 16]);
        gld16(gA + (size_t)(64 + tRow) * K_DIM + k0 + tCol, &lA[4096 + tid * 16]);
        gld16(gB + (size_t)tRow * K_DIM + k0 + tCol,        &lB[tid * 16]);
        gld16(gB + (size_t)(64 + tRow) * K_DIM + k0 + tCol, &lB[4096 + tid * 16]);
        __syncthreads();

        long a0[4], a1[4], b0[4], b1[4];
#pragma unroll
        for (int m = 0; m < 4; ++m) {
            int r = (wr * 64 + m * 16 + lr) * 64;
            a0[m] = *(const long*)&lA[r + lk];
            a1[m] = *(const long*)&lA[r + 32 + lk];
        }
#pragma unroll
        for (int n = 0; n < 4; ++n) {
            int r = (wc * 64 + n * 16 + lr) * 64;
            b0[n] = *(const long*)&lB[r + lk];
            b1[n] = *(const long*)&lB[r + 32 + lk];
        }
#pragma unroll
        for (int m = 0; m < 4; ++m)
#pragma unroll
            for (int n = 0; n < 4; ++n) {
                acc[m][n] = __builtin_amdgcn_mfma_f32_16x16x32_fp8_fp8(
                    a0[m], b0[n], acc[m][n], 0, 0, 0);
                acc[m][n] = __builtin_amdgcn_mfma_f32_16x16x32_fp8_fp8(
                    a1[m], b1[n], acc[m][n], 0, 0, 0);
            }
        __syncthreads();
    }

    // epilogue: scale by (amax_x/448)*(amax_w/448), add bias
    const float ax = fmaxf(__uint_as_float(ws_u[0]), 1e-12f);
    const float aw = fmaxf(__uint_as_float(ws_u[1]), 1e-12f);
    const float inv = (ax * (1.0f / 448.0f)) * (aw * (1.0f / 448.0f));

    const int orow0 = bm * 128 + wr * 64 + (l >> 4) * 4;  // D: row=(lane>>4)*4+reg
    const int ocol0 = bn * 128 + wc * 64 + lr;            // D: col=lane&15
#pragma unroll
    for (int m = 0; m < 4; ++m) {
#pragma unroll
        for (int n = 0; n < 4; ++n) {
            const int col = ocol0 + n * 16;
            const float bv = bias[col];
#pragma unroll
            for (int j = 0; j < 4; ++j) {
                const int row = orow0 + m * 16 + j;
                out[(size_t)row * N_DIM + col] = acc[m][n][j] * inv + bv;
            }
        }
    }
}

// ---------------- launch ----------------
extern "C" void kernel_launch(void* const* d_in, const int* in_sizes, int n_in,
                              void* d_out, int out_size, void* d_ws, size_t ws_size,
                              hipStream_t stream) {
    const float* x    = (const float*)d_in[0];   // [8192, 4096]
    const float* wgt  = (const float*)d_in[1];   // [4096, 4096]
    const float* bias = (const float*)d_in[2];   // [4096]
    float* out = (float*)d_out;                  // [8192, 4096] f32

    unsigned int* ws_u = (unsigned int*)d_ws;
    uint8_t* xq = (uint8_t*)d_ws + 256;
    uint8_t* wq = xq + (size_t)M_DIM * K_DIM;

    init_ws_kernel<<<1, 1, 0, stream>>>(ws_u);
    amax_kernel<<<1024, 256, 0, stream>>>(x,   M_DIM * K_DIM / 4, ws_u + 0);
    amax_kernel<<<1024, 256, 0, stream>>>(wgt, N_DIM * K_DIM / 4, ws_u + 1);
    quant_kernel<<<2048, 256, 0, stream>>>(x,   (unsigned int*)xq, M_DIM * K_DIM / 4, ws_u, 0);
    quant_kernel<<<2048, 256, 0, stream>>>(wgt, (unsigned int*)wq, N_DIM * K_DIM / 4, ws_u, 1);

    gemm_fp8_kernel<<<(M_DIM / 128) * (N_DIM / 128), 256, 0, stream>>>(
        xq, wq, bias, ws_u, out);
}

// Round 2
// 298.610 us; speedup vs baseline: 1.9309x; 1.9309x over previous
//
#include <hip/hip_runtime.h>
#include <stdint.h>

#define M_DIM 8192
#define N_DIM 4096
#define K_DIM 4096

typedef float f32x4 __attribute__((ext_vector_type(4)));

// ---------------- init: zero the two amax slots ----------------
__global__ void init_ws_kernel(unsigned int* ws_u) {
    ws_u[0] = 0u;
    ws_u[1] = 0u;
}

// ---------------- amax reduction (abs-max via uint-bits atomicMax) -------
__global__ __launch_bounds__(256) void amax_kernel(const float* __restrict__ in,
                                                   int n4,
                                                   unsigned int* __restrict__ target) {
    int tid = blockIdx.x * blockDim.x + threadIdx.x;
    int stride = gridDim.x * blockDim.x;
    const float4* p = (const float4*)in;
    float m = 0.0f;
    for (int i = tid; i < n4; i += stride) {
        float4 v = p[i];
        m = fmaxf(m, fmaxf(fmaxf(fabsf(v.x), fabsf(v.y)),
                           fmaxf(fabsf(v.z), fabsf(v.w))));
    }
#pragma unroll
    for (int off = 32; off > 0; off >>= 1)
        m = fmaxf(m, __shfl_down(m, off, 64));
    __shared__ float sm[4];
    if ((threadIdx.x & 63) == 0) sm[threadIdx.x >> 6] = m;
    __syncthreads();
    if (threadIdx.x == 0) {
        m = fmaxf(fmaxf(sm[0], sm[1]), fmaxf(sm[2], sm[3]));
        atomicMax(target, __float_as_uint(m));  // all values >= 0: bit order == float order
    }
}

// ---------------- quantize f32 -> fp8 e4m3fn (packed 4/uint) ----------------
__global__ __launch_bounds__(256) void quant_kernel(const float* __restrict__ in,
                                                    unsigned int* __restrict__ outp,
                                                    int n4,
                                                    const unsigned int* __restrict__ ws_u,
                                                    int slot) {
    float amax = fmaxf(__uint_as_float(ws_u[slot]), 1e-12f);
    float scale = 448.0f / amax;
    int tid = blockIdx.x * blockDim.x + threadIdx.x;
    int stride = gridDim.x * blockDim.x;
    const float4* p = (const float4*)in;
    for (int i = tid; i < n4; i += stride) {
        float4 v = p[i];
        float a = fminf(fmaxf(v.x * scale, -448.0f), 448.0f);
        float b = fminf(fmaxf(v.y * scale, -448.0f), 448.0f);
        float c = fminf(fmaxf(v.z * scale, -448.0f), 448.0f);
        float d = fminf(fmaxf(v.w * scale, -448.0f), 448.0f);
        int w = __builtin_amdgcn_cvt_pk_fp8_f32(a, b, 0, false);   // bytes 0,1
        w = __builtin_amdgcn_cvt_pk_fp8_f32(c, d, w, true);        // bytes 2,3
        outp[i] = (unsigned int)w;
    }
}

// ---------------- fp8 GEMM: out[t][o] = inv * sum_k Xq[t][k]*Wq[o][k] + bias[o] ----
__device__ __forceinline__ void gld16(const void* g, void* l) {
    __builtin_amdgcn_global_load_lds(
        (const __attribute__((address_space(1))) void*)g,
        (__attribute__((address_space(3))) void*)l, 16, 0, 0);
}

// LDS tile: [128 rows][64 B], 16B-chunk XOR swizzle keyed on row bits 1-2:
//   LDS(row, c ^ (((row>>1)&3)<<4)) holds global (row, c)
// Stage side: dest chunk qd at row r sources global chunk qd ^ ((r>>1)&3)
// (16 contiguous bytes per lane -> compatible with global_load_lds).
// Read side: addr = row*64 + (c ^ (((row>>1)&3)<<4)).
// Bank math: bank = 16*(row&1) + ((c>>2) ^ (((row>>1)&3)<<2)) -> a 16-lane
// quarter (16 consecutive rows, fixed c) spreads over 8 banks x 2 lanes:
// 2-way (free); full-wave b64 hits the 4-touch/bank floor exactly.
__global__ __launch_bounds__(256, 2) void gemm_fp8_kernel(
    const uint8_t* __restrict__ Aq,   // [M][K] fp8
    const uint8_t* __restrict__ Bq,   // [N][K] fp8 (weight, K-major)
    const float* __restrict__ bias,   // [N]
    const unsigned int* __restrict__ ws_u,
    float* __restrict__ out)          // [M][N] f32
{
    __shared__ uint8_t lA[128 * 64];
    __shared__ uint8_t lB[128 * 64];

    const int tid = threadIdx.x;
    const int w = tid >> 6, l = tid & 63;

    // XCD-aware swizzle (gridDim.x == 2048, divisible by 8)
    const int nwg = gridDim.x;
    const int cpx = nwg >> 3;
    const int bid = blockIdx.x;
    const int swz = (bid & 7) * cpx + (bid >> 3);
    const int NT = N_DIM / 128;          // 32 col-tiles
    const int bm = swz / NT, bn = swz % NT;

    const uint8_t* gA = Aq + (size_t)bm * 128 * K_DIM;
    const uint8_t* gB = Bq + (size_t)bn * 128 * K_DIM;

    // staging map: thread t -> lds row tRow (and 64+tRow), dest 16B chunk qd.
    // source col chunk = qd ^ ((row>>1)&3); note (64+tRow) has same swizzle key.
    const int tRow = tid >> 2;
    const int qd = tid & 3;
    const int wkey = (tRow >> 1) & 3;
    const int srcCol = (qd ^ wkey) << 4;

    f32x4 acc[4][4] = {};
    const int wr = w >> 1, wc = w & 1;   // 2x2 wave grid, 64x64 per wave
    const int lr = l & 15;
    const int g = l >> 4;
    const int c0 = g << 3;               // k-byte offset within 32-wide k group
    const int c1 = 32 + (g << 3);

    for (int k0 = 0; k0 < K_DIM; k0 += 64) {
        gld16(gA + (size_t)tRow * K_DIM + k0 + srcCol,        &lA[tid * 16]);
        gld16(gA + (size_t)(64 + tRow) * K_DIM + k0 + srcCol, &lA[4096 + tid * 16]);
        gld16(gB + (size_t)tRow * K_DIM + k0 + srcCol,        &lB[tid * 16]);
        gld16(gB + (size_t)(64 + tRow) * K_DIM + k0 + srcCol, &lB[4096 + tid * 16]);
        __syncthreads();

        long a0[4], a1[4], b0[4], b1[4];
#pragma unroll
        for (int m = 0; m < 4; ++m) {
            int row = wr * 64 + m * 16 + lr;
            int base = row << 6;
            int wz = ((row >> 1) & 3) << 4;
            a0[m] = *(const long*)&lA[base + (c0 ^ wz)];
            a1[m] = *(const long*)&lA[base + (c1 ^ wz)];
        }
#pragma unroll
        for (int n = 0; n < 4; ++n) {
            int row = wc * 64 + n * 16 + lr;
            int base = row << 6;
            int wz = ((row >> 1) & 3) << 4;
            b0[n] = *(const long*)&lB[base + (c0 ^ wz)];
            b1[n] = *(const long*)&lB[base + (c1 ^ wz)];
        }
#pragma unroll
        for (int m = 0; m < 4; ++m)
#pragma unroll
            for (int n = 0; n < 4; ++n) {
                acc[m][n] = __builtin_amdgcn_mfma_f32_16x16x32_fp8_fp8(
                    a0[m], b0[n], acc[m][n], 0, 0, 0);
                acc[m][n] = __builtin_amdgcn_mfma_f32_16x16x32_fp8_fp8(
                    a1[m], b1[n], acc[m][n], 0, 0, 0);
            }
        __syncthreads();
    }

    // epilogue: scale by (amax_x/448)*(amax_w/448), add bias
    const float ax = fmaxf(__uint_as_float(ws_u[0]), 1e-12f);
    const float aw = fmaxf(__uint_as_float(ws_u[1]), 1e-12f);
    const float inv = (ax * (1.0f / 448.0f)) * (aw * (1.0f / 448.0f));

    const int orow0 = bm * 128 + wr * 64 + g * 4;         // D: row=(lane>>4)*4+reg
    const int ocol0 = bn * 128 + wc * 64 + lr;            // D: col=lane&15
#pragma unroll
    for (int m = 0; m < 4; ++m) {
#pragma unroll
        for (int n = 0; n < 4; ++n) {
            const int col = ocol0 + n * 16;
            const float bv = bias[col];
#pragma unroll
            for (int j = 0; j < 4; ++j) {
                const int row = orow0 + m * 16 + j;
                out[(size_t)row * N_DIM + col] = acc[m][n][j] * inv + bv;
            }
        }
    }
}

// ---------------- launch ----------------
extern "C" void kernel_launch(void* const* d_in, const int* in_sizes, int n_in,
                              void* d_out, int out_size, void* d_ws, size_t ws_size,
                              hipStream_t stream) {
    const float* x    = (const float*)d_in[0];   // [8192, 4096]
    const float* wgt  = (const float*)d_in[1];   // [4096, 4096]
    const float* bias = (const float*)d_in[2];   // [4096]
    float* out = (float*)d_out;                  // [8192, 4096] f32

    unsigned int* ws_u = (unsigned int*)d_ws;
    uint8_t* xq = (uint8_t*)d_ws + 256;
    uint8_t* wq = xq + (size_t)M_DIM * K_DIM;

    init_ws_kernel<<<1, 1, 0, stream>>>(ws_u);
    amax_kernel<<<1024, 256, 0, stream>>>(x,   M_DIM * K_DIM / 4, ws_u + 0);
    amax_kernel<<<1024, 256, 0, stream>>>(wgt, N_DIM * K_DIM / 4, ws_u + 1);
    quant_kernel<<<2048, 256, 0, stream>>>(x,   (unsigned int*)xq, M_DIM * K_DIM / 4, ws_u, 0);
    quant_kernel<<<2048, 256, 0, stream>>>(wgt, (unsigned int*)wq, N_DIM * K_DIM / 4, ws_u, 1);

    gemm_fp8_kernel<<<(M_DIM / 128) * (N_DIM / 128), 256, 0, stream>>>(
        xq, wq, bias, ws_u, out);
}

// Round 3
// 279.148 us; speedup vs baseline: 2.0655x; 1.0697x over previous
//
#include <hip/hip_runtime.h>
#include <stdint.h>

#define M_DIM 8192
#define N_DIM 4096
#define K_DIM 4096

typedef float f32x4 __attribute__((ext_vector_type(4)));
typedef int   i32x4 __attribute__((ext_vector_type(4)));
typedef int   i32x8 __attribute__((ext_vector_type(8)));

// ---------------- init: zero the two amax slots ----------------
__global__ void init_ws_kernel(unsigned int* ws_u) {
    ws_u[0] = 0u;
    ws_u[1] = 0u;
}

// ---------------- amax reduction (abs-max via uint-bits atomicMax) -------
__global__ __launch_bounds__(256) void amax_kernel(const float* __restrict__ in,
                                                   int n4,
                                                   unsigned int* __restrict__ target) {
    int tid = blockIdx.x * blockDim.x + threadIdx.x;
    int stride = gridDim.x * blockDim.x;
    const float4* p = (const float4*)in;
    float m = 0.0f;
    for (int i = tid; i < n4; i += stride) {
        float4 v = p[i];
        m = fmaxf(m, fmaxf(fmaxf(fabsf(v.x), fabsf(v.y)),
                           fmaxf(fabsf(v.z), fabsf(v.w))));
    }
#pragma unroll
    for (int off = 32; off > 0; off >>= 1)
        m = fmaxf(m, __shfl_down(m, off, 64));
    __shared__ float sm[4];
    if ((threadIdx.x & 63) == 0) sm[threadIdx.x >> 6] = m;
    __syncthreads();
    if (threadIdx.x == 0) {
        m = fmaxf(fmaxf(sm[0], sm[1]), fmaxf(sm[2], sm[3]));
        atomicMax(target, __float_as_uint(m));  // all values >= 0: bit order == float order
    }
}

// ---------------- quantize f32 -> fp8 e4m3fn (packed 4/uint) ----------------
__global__ __launch_bounds__(256) void quant_kernel(const float* __restrict__ in,
                                                    unsigned int* __restrict__ outp,
                                                    int n4,
                                                    const unsigned int* __restrict__ ws_u,
                                                    int slot) {
    float amax = fmaxf(__uint_as_float(ws_u[slot]), 1e-12f);
    float scale = 448.0f / amax;
    int tid = blockIdx.x * blockDim.x + threadIdx.x;
    int stride = gridDim.x * blockDim.x;
    const float4* p = (const float4*)in;
    for (int i = tid; i < n4; i += stride) {
        float4 v = p[i];
        float a = fminf(fmaxf(v.x * scale, -448.0f), 448.0f);
        float b = fminf(fmaxf(v.y * scale, -448.0f), 448.0f);
        float c = fminf(fmaxf(v.z * scale, -448.0f), 448.0f);
        float d = fminf(fmaxf(v.w * scale, -448.0f), 448.0f);
        int w = __builtin_amdgcn_cvt_pk_fp8_f32(a, b, 0, false);   // bytes 0,1
        w = __builtin_amdgcn_cvt_pk_fp8_f32(c, d, w, true);        // bytes 2,3
        outp[i] = (unsigned int)w;
    }
}

// ---------------- MX-fp8 GEMM (scale==1.0 -> exact fp8 dot products) ----------
__device__ __forceinline__ void gld16(const void* g, void* l) {
    __builtin_amdgcn_global_load_lds(
        (const __attribute__((address_space(1))) void*)g,
        (__attribute__((address_space(3))) void*)l, 16, 0, 0);
}

// LDS tile: [128 rows][128 B]. 16B-chunk XOR swizzle: LDS chunk ch holds
// global chunk ch ^ (row&7). Stage: linear dest (tid*16 + round*4096),
// per-lane global source chunk = p ^ (row&7)  (row&7 invariant across the
// 32-row rounds). Read: lane fragment = 32 B = two ds_read_b128 at chunks
// (2g)^(row&7), (2g+1)^(row&7). Per 16-lane quarter the XOR bijects over
// all 8 chunks -> 2 lanes/chunk -> wave hits the 8-touch/bank b128 floor.
__global__ __launch_bounds__(256, 2) void gemm_fp8_kernel(
    const uint8_t* __restrict__ Aq,   // [M][K] fp8
    const uint8_t* __restrict__ Bq,   // [N][K] fp8 (weight, K-major)
    const float* __restrict__ bias,   // [N]
    const unsigned int* __restrict__ ws_u,
    float* __restrict__ out)          // [M][N] f32
{
    __shared__ uint8_t lA[128 * 128];
    __shared__ uint8_t lB[128 * 128];

    const int tid = threadIdx.x;
    const int w = tid >> 6, l = tid & 63;

    // XCD-aware swizzle (gridDim.x == 2048, divisible by 8)
    const int nwg = gridDim.x;
    const int cpx = nwg >> 3;
    const int bid = blockIdx.x;
    const int swz = (bid & 7) * cpx + (bid >> 3);
    const int NT = N_DIM / 128;          // 32 col-tiles
    const int bm = swz / NT, bn = swz % NT;

    const uint8_t* gA = Aq + (size_t)bm * 128 * K_DIM;
    const uint8_t* gB = Bq + (size_t)bn * 128 * K_DIM;

    // staging: thread t -> row sRow+32*i (i=0..3), dest chunk p, src chunk p^(row&7)
    const int sRow = tid >> 3;           // 0..31
    const int p    = tid & 7;
    const int srcOff = ((p ^ (sRow & 7)) << 4);

    f32x4 acc[4][4] = {};
    const int wr = w >> 1, wc = w & 1;   // 2x2 wave grid, 64x64 per wave
    const int lr = l & 15;
    const int g = l >> 4;                // k-group: lane holds k-bytes [g*32, g*32+32)

    for (int k0 = 0; k0 < K_DIM; k0 += 128) {
#pragma unroll
        for (int i = 0; i < 4; ++i)
            gld16(gA + (size_t)(sRow + 32 * i) * K_DIM + k0 + srcOff,
                  &lA[i * 4096 + tid * 16]);
#pragma unroll
        for (int i = 0; i < 4; ++i)
            gld16(gB + (size_t)(sRow + 32 * i) * K_DIM + k0 + srcOff,
                  &lB[i * 4096 + tid * 16]);
        __syncthreads();

        i32x8 av[4], bv[4];
#pragma unroll
        for (int m = 0; m < 4; ++m) {
            int row = wr * 64 + m * 16 + lr;
            int base = row << 7;
            int rk = row & 7;
            i32x4 lo = *(const i32x4*)&lA[base + (((2 * g) ^ rk) << 4)];
            i32x4 hi = *(const i32x4*)&lA[base + (((2 * g + 1) ^ rk) << 4)];
            av[m] = __builtin_shufflevector(lo, hi, 0, 1, 2, 3, 4, 5, 6, 7);
        }
#pragma unroll
        for (int n = 0; n < 4; ++n) {
            int row = wc * 64 + n * 16 + lr;
            int base = row << 7;
            int rk = row & 7;
            i32x4 lo = *(const i32x4*)&lB[base + (((2 * g) ^ rk) << 4)];
            i32x4 hi = *(const i32x4*)&lB[base + (((2 * g + 1) ^ rk) << 4)];
            bv[n] = __builtin_shufflevector(lo, hi, 0, 1, 2, 3, 4, 5, 6, 7);
        }
#pragma unroll
        for (int m = 0; m < 4; ++m)
#pragma unroll
            for (int n = 0; n < 4; ++n)
                acc[m][n] = __builtin_amdgcn_mfma_scale_f32_16x16x128_f8f6f4(
                    av[m], bv[n], acc[m][n],
                    0, 0,                 // cbsz=FP8(e4m3), blgp=FP8(e4m3)
                    0, 0x7F7F7F7F,        // scale_a opsel, scale_a = 1.0 (E8M0 127)
                    0, 0x7F7F7F7F);       // scale_b opsel, scale_b = 1.0
        __syncthreads();
    }

    // epilogue: scale by (amax_x/448)*(amax_w/448), add bias
    const float ax = fmaxf(__uint_as_float(ws_u[0]), 1e-12f);
    const float aw = fmaxf(__uint_as_float(ws_u[1]), 1e-12f);
    const float inv = (ax * (1.0f / 448.0f)) * (aw * (1.0f / 448.0f));

    const int orow0 = bm * 128 + wr * 64 + g * 4;         // D: row=(lane>>4)*4+reg
    const int ocol0 = bn * 128 + wc * 64 + lr;            // D: col=lane&15
#pragma unroll
    for (int m = 0; m < 4; ++m) {
#pragma unroll
        for (int n = 0; n < 4; ++n) {
            const int col = ocol0 + n * 16;
            const float bv = bias[col];
#pragma unroll
            for (int j = 0; j < 4; ++j) {
                const int row = orow0 + m * 16 + j;
                out[(size_t)row * N_DIM + col] = acc[m][n][j] * inv + bv;
            }
        }
    }
}

// ---------------- launch ----------------
extern "C" void kernel_launch(void* const* d_in, const int* in_sizes, int n_in,
                              void* d_out, int out_size, void* d_ws, size_t ws_size,
                              hipStream_t stream) {
    const float* x    = (const float*)d_in[0];   // [8192, 4096]
    const float* wgt  = (const float*)d_in[1];   // [4096, 4096]
    const float* bias = (const float*)d_in[2];   // [4096]
    float* out = (float*)d_out;                  // [8192, 4096] f32

    unsigned int* ws_u = (unsigned int*)d_ws;
    uint8_t* xq = (uint8_t*)d_ws + 256;
    uint8_t* wq = xq + (size_t)M_DIM * K_DIM;

    init_ws_kernel<<<1, 1, 0, stream>>>(ws_u);
    amax_kernel<<<1024, 256, 0, stream>>>(x,   M_DIM * K_DIM / 4, ws_u + 0);
    amax_kernel<<<1024, 256, 0, stream>>>(wgt, N_DIM * K_DIM / 4, ws_u + 1);
    quant_kernel<<<2048, 256, 0, stream>>>(x,   (unsigned int*)xq, M_DIM * K_DIM / 4, ws_u, 0);
    quant_kernel<<<2048, 256, 0, stream>>>(wgt, (unsigned int*)wq, N_DIM * K_DIM / 4, ws_u, 1);

    gemm_fp8_kernel<<<(M_DIM / 128) * (N_DIM / 128), 256, 0, stream>>>(
        xq, wq, bias, ws_u, out);
}

// Round 4
// 219.486 us; speedup vs baseline: 2.6270x; 1.2718x over previous
//
#include <hip/hip_runtime.h>
#include <stdint.h>

#define M_DIM 8192
#define N_DIM 4096
#define K_DIM 4096

typedef float f32x4 __attribute__((ext_vector_type(4)));
typedef int   i32x4 __attribute__((ext_vector_type(4)));
typedef int   i32x8 __attribute__((ext_vector_type(8)));

// ---------------- init: zero the two amax slots ----------------
__global__ void init_ws_kernel(unsigned int* ws_u) {
    ws_u[0] = 0u;
    ws_u[1] = 0u;
}

// ---------------- amax reduction (abs-max via uint-bits atomicMax) -------
__global__ __launch_bounds__(256) void amax_kernel(const float* __restrict__ in,
                                                   int n4,
                                                   unsigned int* __restrict__ target) {
    int tid = blockIdx.x * blockDim.x + threadIdx.x;
    int stride = gridDim.x * blockDim.x;
    const float4* p = (const float4*)in;
    float m = 0.0f;
    for (int i = tid; i < n4; i += stride) {
        float4 v = p[i];
        m = fmaxf(m, fmaxf(fmaxf(fabsf(v.x), fabsf(v.y)),
                           fmaxf(fabsf(v.z), fabsf(v.w))));
    }
#pragma unroll
    for (int off = 32; off > 0; off >>= 1)
        m = fmaxf(m, __shfl_down(m, off, 64));
    __shared__ float sm[4];
    if ((threadIdx.x & 63) == 0) sm[threadIdx.x >> 6] = m;
    __syncthreads();
    if (threadIdx.x == 0) {
        m = fmaxf(fmaxf(sm[0], sm[1]), fmaxf(sm[2], sm[3]));
        atomicMax(target, __float_as_uint(m));  // all values >= 0: bit order == float order
    }
}

// ---------------- quantize f32 -> fp8 e4m3fn (packed 4/uint) ----------------
__global__ __launch_bounds__(256) void quant_kernel(const float* __restrict__ in,
                                                    unsigned int* __restrict__ outp,
                                                    int n4,
                                                    const unsigned int* __restrict__ ws_u,
                                                    int slot) {
    float amax = fmaxf(__uint_as_float(ws_u[slot]), 1e-12f);
    float scale = 448.0f / amax;
    int tid = blockIdx.x * blockDim.x + threadIdx.x;
    int stride = gridDim.x * blockDim.x;
    const float4* p = (const float4*)in;
    for (int i = tid; i < n4; i += stride) {
        float4 v = p[i];
        float a = fminf(fmaxf(v.x * scale, -448.0f), 448.0f);
        float b = fminf(fmaxf(v.y * scale, -448.0f), 448.0f);
        float c = fminf(fmaxf(v.z * scale, -448.0f), 448.0f);
        float d = fminf(fmaxf(v.w * scale, -448.0f), 448.0f);
        int w = __builtin_amdgcn_cvt_pk_fp8_f32(a, b, 0, false);   // bytes 0,1
        w = __builtin_amdgcn_cvt_pk_fp8_f32(c, d, w, true);        // bytes 2,3
        outp[i] = (unsigned int)w;
    }
}

// ---------------- MX-fp8 GEMM, 256x256 tile, 4-phase pipelined ----------------
__device__ __forceinline__ void gld16(const void* g, void* l) {
    __builtin_amdgcn_global_load_lds(
        (const __attribute__((address_space(1))) void*)g,
        (__attribute__((address_space(3))) void*)l, 16, 0, 0);
}

#define MFMA_MX(a, b, c) __builtin_amdgcn_mfma_scale_f32_16x16x128_f8f6f4( \
    (a), (b), (c), 0, 0, 0, 0x7F7F7F7F, 0, 0x7F7F7F7F)

// LDS: A bufs at [0,32K),[32K,64K); B bufs at [64K,96K),[96K,128K).
// Per-tensor tile [256 rows][128 B], 16B-chunk XOR swizzle (chunk ^= row&7),
// staged linearly (pre-swizzled global source), read with XOR on address.
// Pipeline: tile t read from buf t&1; tile t+1's 4 units staged one-per-phase
// into buf^1. Counted vmcnt only: ledger (2 loads/unit, issue order
// UA0,UB0,UA1,UB1 per tile) => phase0 needs UA0,UB0 -> vmcnt(4);
// phase1 needs UA1,UB1 -> vmcnt(2). Never 0 in the main loop.
__global__ __launch_bounds__(512, 2) void gemm_fp8_kernel(
    const uint8_t* __restrict__ Aq,   // [M][K] fp8
    const uint8_t* __restrict__ Bq,   // [N][K] fp8
    const float* __restrict__ bias,   // [N]
    const unsigned int* __restrict__ ws_u,
    float* __restrict__ out)          // [M][N] f32
{
    __shared__ uint8_t lds[131072];

    const int tid = threadIdx.x;
    const int w = tid >> 6, l = tid & 63;

    // XCD swizzle (512 blocks, %8==0): 32 M-tiles x 16 N-tiles
    const int cpx = (int)gridDim.x >> 3;
    const int bid = (int)blockIdx.x;
    const int swz = (bid & 7) * cpx + (bid >> 3);
    const int bm = swz >> 4, bn = swz & 15;

    const uint8_t* gA = Aq + (size_t)bm * 256 * K_DIM;
    const uint8_t* gB = Bq + (size_t)bn * 256 * K_DIM;

    // staging constants
    const int idx = tid >> 3, p = tid & 7;
    const int rB = (idx & 31) + ((idx >> 5) << 6);
    const int srcX = ((p ^ (idx & 7)) << 4);
    const int dA = tid * 16;
    const int dB = tid * 16 + ((tid >> 8) << 12);

    // fragment-read constants
    const int wr = w >> 2, wc = w & 3;       // 2M x 4N wave grid
    const int lr = l & 15, g = l >> 4;
    const int oLo = (((2 * g) ^ (lr & 7)) << 4);
    const int oHi = (((2 * g + 1) ^ (lr & 7)) << 4);
    const int rowA0 = wr * 128 + lr;
    const int rowB0 = wc * 64 + lr;

    auto stA = [&](int bb, const uint8_t* gsrc, int rbase) {
        const int row = idx + rbase;
        gld16(gsrc + (size_t)row * K_DIM + srcX,
              &lds[bb * 32768 + rbase * 128 + dA]);
    };
    auto stB = [&](int bb, const uint8_t* gsrc, int boff, int r) {
        const int row = rB + boff + (r << 7);
        gld16(gsrc + (size_t)row * K_DIM + srcX,
              &lds[65536 + bb * 32768 + (boff << 7) + (r << 14) + dB]);
    };
    auto ldf = [&](const uint8_t* base, int row) -> i32x8 {
        const uint8_t* q = base + (row << 7);
        i32x4 lo = *(const i32x4*)(q + oLo);
        i32x4 hi = *(const i32x4*)(q + oHi);
        return __builtin_shufflevector(lo, hi, 0, 1, 2, 3, 4, 5, 6, 7);
    };

    f32x4 acc[8][4] = {};
    i32x8 av[4], bv[4];

    // prologue: stage tile 0 -> buf 0 (issue order UA0, UB0, UA1, UB1)
    stA(0, gA, 0);   stA(0, gA, 128);
    stB(0, gB, 0, 0); stB(0, gB, 0, 1);
    stA(0, gA, 64);  stA(0, gA, 192);
    stB(0, gB, 32, 0); stB(0, gB, 32, 1);

    for (int t = 0; t < 31; ++t) {
        const int buf = t & 1, nbuf = buf ^ 1;
        const uint8_t* gAn = gA + (size_t)(t + 1) * 128;
        const uint8_t* gBn = gB + (size_t)(t + 1) * 128;
        const uint8_t* lab = &lds[buf * 32768];
        const uint8_t* lbb = &lds[65536 + buf * 32768];

        // ---- phase 0: UA0(t),UB0(t) ready; stage UA0(t+1)
        asm volatile("s_waitcnt vmcnt(4)" ::: "memory");
        __builtin_amdgcn_s_barrier();
        stA(nbuf, gAn, 0); stA(nbuf, gAn, 128);
        av[0] = ldf(lab, rowA0);      av[1] = ldf(lab, rowA0 + 16);
        av[2] = ldf(lab, rowA0 + 32); av[3] = ldf(lab, rowA0 + 48);
        bv[0] = ldf(lbb, rowB0);      bv[1] = ldf(lbb, rowB0 + 16);
        __builtin_amdgcn_s_setprio(1);
        acc[0][0] = MFMA_MX(av[0], bv[0], acc[0][0]);
        acc[0][1] = MFMA_MX(av[0], bv[1], acc[0][1]);
        acc[1][0] = MFMA_MX(av[1], bv[0], acc[1][0]);
        acc[1][1] = MFMA_MX(av[1], bv[1], acc[1][1]);
        acc[2][0] = MFMA_MX(av[2], bv[0], acc[2][0]);
        acc[2][1] = MFMA_MX(av[2], bv[1], acc[2][1]);
        acc[3][0] = MFMA_MX(av[3], bv[0], acc[3][0]);
        acc[3][1] = MFMA_MX(av[3], bv[1], acc[3][1]);
        __builtin_amdgcn_s_setprio(0);

        // ---- phase 1: UA1(t),UB1(t) ready; stage UB0(t+1)
        asm volatile("s_waitcnt vmcnt(2)" ::: "memory");
        __builtin_amdgcn_s_barrier();
        stB(nbuf, gBn, 0, 0); stB(nbuf, gBn, 0, 1);
        bv[2] = ldf(lbb, rowB0 + 32); bv[3] = ldf(lbb, rowB0 + 48);
        __builtin_amdgcn_s_setprio(1);
        acc[0][2] = MFMA_MX(av[0], bv[2], acc[0][2]);
        acc[0][3] = MFMA_MX(av[0], bv[3], acc[0][3]);
        acc[1][2] = MFMA_MX(av[1], bv[2], acc[1][2]);
        acc[1][3] = MFMA_MX(av[1], bv[3], acc[1][3]);
        acc[2][2] = MFMA_MX(av[2], bv[2], acc[2][2]);
        acc[2][3] = MFMA_MX(av[2], bv[3], acc[2][3]);
        acc[3][2] = MFMA_MX(av[3], bv[2], acc[3][2]);
        acc[3][3] = MFMA_MX(av[3], bv[3], acc[3][3]);
        __builtin_amdgcn_s_setprio(0);

        // ---- phase 2: stage UA1(t+1); read A mb4-7 (completion covered by ph1)
        stA(nbuf, gAn, 64); stA(nbuf, gAn, 192);
        av[0] = ldf(lab, rowA0 + 64); av[1] = ldf(lab, rowA0 + 80);
        av[2] = ldf(lab, rowA0 + 96); av[3] = ldf(lab, rowA0 + 112);
        __builtin_amdgcn_s_setprio(1);
        acc[4][0] = MFMA_MX(av[0], bv[0], acc[4][0]);
        acc[4][1] = MFMA_MX(av[0], bv[1], acc[4][1]);
        acc[5][0] = MFMA_MX(av[1], bv[0], acc[5][0]);
        acc[5][1] = MFMA_MX(av[1], bv[1], acc[5][1]);
        acc[6][0] = MFMA_MX(av[2], bv[0], acc[6][0]);
        acc[6][1] = MFMA_MX(av[2], bv[1], acc[6][1]);
        acc[7][0] = MFMA_MX(av[3], bv[0], acc[7][0]);
        acc[7][1] = MFMA_MX(av[3], bv[1], acc[7][1]);
        __builtin_amdgcn_s_setprio(0);

        // ---- phase 3: stage UB1(t+1)
        stB(nbuf, gBn, 32, 0); stB(nbuf, gBn, 32, 1);
        __builtin_amdgcn_s_setprio(1);
        acc[4][2] = MFMA_MX(av[0], bv[2], acc[4][2]);
        acc[4][3] = MFMA_MX(av[0], bv[3], acc[4][3]);
        acc[5][2] = MFMA_MX(av[1], bv[2], acc[5][2]);
        acc[5][3] = MFMA_MX(av[1], bv[3], acc[5][3]);
        acc[6][2] = MFMA_MX(av[2], bv[2], acc[6][2]);
        acc[6][3] = MFMA_MX(av[2], bv[3], acc[6][3]);
        acc[7][2] = MFMA_MX(av[3], bv[2], acc[7][2]);
        acc[7][3] = MFMA_MX(av[3], bv[3], acc[7][3]);
        __builtin_amdgcn_s_setprio(0);
    }

    // ---- peeled last tile (t=31, buf=1): no stages; drain waits
    {
        const uint8_t* lab = &lds[32768];
        const uint8_t* lbb = &lds[65536 + 32768];

        asm volatile("s_waitcnt vmcnt(4)" ::: "memory");
        __builtin_amdgcn_s_barrier();
        av[0] = ldf(lab, rowA0);      av[1] = ldf(lab, rowA0 + 16);
        av[2] = ldf(lab, rowA0 + 32); av[3] = ldf(lab, rowA0 + 48);
        bv[0] = ldf(lbb, rowB0);      bv[1] = ldf(lbb, rowB0 + 16);
#pragma unroll
        for (int m = 0; m < 4; ++m) {
            acc[m][0] = MFMA_MX(av[m], bv[0], acc[m][0]);
            acc[m][1] = MFMA_MX(av[m], bv[1], acc[m][1]);
        }
        asm volatile("s_waitcnt vmcnt(0)" ::: "memory");
        __builtin_amdgcn_s_barrier();
        bv[2] = ldf(lbb, rowB0 + 32); bv[3] = ldf(lbb, rowB0 + 48);
#pragma unroll
        for (int m = 0; m < 4; ++m) {
            acc[m][2] = MFMA_MX(av[m], bv[2], acc[m][2]);
            acc[m][3] = MFMA_MX(av[m], bv[3], acc[m][3]);
        }
        av[0] = ldf(lab, rowA0 + 64); av[1] = ldf(lab, rowA0 + 80);
        av[2] = ldf(lab, rowA0 + 96); av[3] = ldf(lab, rowA0 + 112);
#pragma unroll
        for (int m = 0; m < 4; ++m) {
            acc[4 + m][0] = MFMA_MX(av[m], bv[0], acc[4 + m][0]);
            acc[4 + m][1] = MFMA_MX(av[m], bv[1], acc[4 + m][1]);
            acc[4 + m][2] = MFMA_MX(av[m], bv[2], acc[4 + m][2]);
            acc[4 + m][3] = MFMA_MX(av[m], bv[3], acc[4 + m][3]);
        }
    }

    // ---- epilogue: scale by (amax_x/448)*(amax_w/448), add bias
    const float ax = fmaxf(__uint_as_float(ws_u[0]), 1e-12f);
    const float aw = fmaxf(__uint_as_float(ws_u[1]), 1e-12f);
    const float inv = (ax * (1.0f / 448.0f)) * (aw * (1.0f / 448.0f));

    const int orow0 = bm * 256 + wr * 128 + g * 4;   // D: row=(lane>>4)*4+reg
    const int ocol0 = bn * 256 + wc * 64 + lr;       // D: col=lane&15
#pragma unroll
    for (int mb = 0; mb < 8; ++mb) {
#pragma unroll
        for (int nb = 0; nb < 4; ++nb) {
            const int col = ocol0 + nb * 16;
            const float bvv = bias[col];
#pragma unroll
            for (int j = 0; j < 4; ++j) {
                const int row = orow0 + mb * 16 + j;
                out[(size_t)row * N_DIM + col] = acc[mb][nb][j] * inv + bvv;
            }
        }
    }
}

// ---------------- launch ----------------
extern "C" void kernel_launch(void* const* d_in, const int* in_sizes, int n_in,
                              void* d_out, int out_size, void* d_ws, size_t ws_size,
                              hipStream_t stream) {
    const float* x    = (const float*)d_in[0];   // [8192, 4096]
    const float* wgt  = (const float*)d_in[1];   // [4096, 4096]
    const float* bias = (const float*)d_in[2];   // [4096]
    float* out = (float*)d_out;                  // [8192, 4096] f32

    unsigned int* ws_u = (unsigned int*)d_ws;
    uint8_t* xq = (uint8_t*)d_ws + 256;
    uint8_t* wq = xq + (size_t)M_DIM * K_DIM;

    init_ws_kernel<<<1, 1, 0, stream>>>(ws_u);
    amax_kernel<<<1024, 256, 0, stream>>>(x,   M_DIM * K_DIM / 4, ws_u + 0);
    amax_kernel<<<1024, 256, 0, stream>>>(wgt, N_DIM * K_DIM / 4, ws_u + 1);
    quant_kernel<<<2048, 256, 0, stream>>>(x,   (unsigned int*)xq, M_DIM * K_DIM / 4, ws_u, 0);
    quant_kernel<<<2048, 256, 0, stream>>>(wgt, (unsigned int*)wq, N_DIM * K_DIM / 4, ws_u, 1);

    gemm_fp8_kernel<<<(M_DIM / 256) * (N_DIM / 256), 512, 0, stream>>>(
        xq, wq, bias, ws_u, out);
}